// Round 1
// baseline (616.917 us; speedup 1.0000x reference)
//
#include <hip/hip_runtime.h>
#include <hip/hip_bf16.h>

// SubtractionGaussian: out[b,h,i,j] = ||q_i||^2 + ||k_j||^2 - 2 q_i.k_j
// B=4 H=8 Lq=Lk=2048 D=64, fp32 in/out. Output = 537 MB -> write-bound.
// bf16 MFMA 16x16x32; BOTH operands staged [row][k] in LDS (K transposed on
// stage) so every fragment is one aligned ds_read_b128.
//
// This version: DIRECT-STORE epilogue. The previous LDS-staged float4 epilogue
// cost 5 barriers/block + a full LDS round trip of the output with half the
// waves idle; stores were bursty and the kernel ran at ~2.5 TB/s effective vs
// the ~6.1 TB/s the fill kernel proves. Direct scalar stores emit 4x64B full
// L2 sectors per wave-instr (consecutive ni instrs complete each 128B line),
// no RMW. Barriers: 2 total. Norms are now fused into the staging pass as
// fp32 squares of in-register values (LDS atomicAdd) -- removes the separate
// bf16-unpack norms pass AND is more accurate than bf16-rounded norms.

#define BH 32
#define LQ 2048
#define LK 2048
#define DD 64
#define TM 128
#define TN 128
#define LDT 72    // ushorts per LDS tile row (64 + 8 pad) -> 144 B stride

typedef __attribute__((ext_vector_type(8))) short short8;
typedef __attribute__((ext_vector_type(4))) float f32x4;

__device__ __forceinline__ unsigned f2bf(float f) {
  unsigned u = __builtin_bit_cast(unsigned, f);
  u += 0x7fffu + ((u >> 16) & 1u);  // RNE
  return u >> 16;
}

__global__ __launch_bounds__(256, 4) void sg_kernel(const float* __restrict__ Q,
                                                    const float* __restrict__ K,
                                                    float* __restrict__ out) {
  __shared__ __align__(16) unsigned short smem[2 * TM * LDT];  // 36,864 B
  __shared__ __align__(16) float norms[256];  // [0..127]=||q_m||^2, [128..255]=||k_n||^2

  unsigned short* As = smem;
  unsigned short* Bt = smem + TM * LDT;

  const int bh  = blockIdx.z;
  const int gm0 = blockIdx.y * TM;
  const int gn0 = blockIdx.x * TN;
  const int tid = threadIdx.x;

  norms[tid] = 0.f;
  __syncthreads();

  // ---- stage A: Q tile [m][k], 8-float chunks -> one b128 LDS write each.
  // fp32 row-norm partials accumulated from the in-register values. ----
  {
    const float* qbase = Q + ((size_t)bh * LQ + gm0) * DD;
#pragma unroll
    for (int it = 0; it < 4; ++it) {
      int c = it * 256 + tid;  // 8-float chunk id, 0..1023 (128 rows x 8 chunks)
      const float4* p = (const float4*)(qbase + c * 8);
      float4 a = p[0];
      float4 b = p[1];
      float s = a.x * a.x + a.y * a.y + a.z * a.z + a.w * a.w +
                b.x * b.x + b.y * b.y + b.z * b.z + b.w * b.w;
      atomicAdd(&norms[c >> 3], s);
      int4 pk;
      pk.x = (int)(f2bf(a.x) | (f2bf(a.y) << 16));
      pk.y = (int)(f2bf(a.z) | (f2bf(a.w) << 16));
      pk.z = (int)(f2bf(b.x) | (f2bf(b.y) << 16));
      pk.w = (int)(f2bf(b.z) | (f2bf(b.w) << 16));
      *(int4*)&As[(c >> 3) * LDT + (c & 7) * 8] = pk;
    }
  }

  // ---- stage B transposed: Bt[n][k]. Coalesced scalar loads (4 rows of one
  // column), pack 4 bf16 -> ds_write_b64. fp32 col-norm partials fused. ----
  {
    int col = tid & 127;
    int c0b = (tid >> 7) * 32;  // threads 0-127 do k 0..31, 128-255 do k 32..63
    const float* kp = K + (size_t)bh * DD * LK + gn0 + col;
    float s = 0.f;
#pragma unroll
    for (int it = 0; it < 8; ++it) {
      int c0 = c0b + it * 4;
      float v0 = kp[(size_t)(c0 + 0) * LK];
      float v1 = kp[(size_t)(c0 + 1) * LK];
      float v2 = kp[(size_t)(c0 + 2) * LK];
      float v3 = kp[(size_t)(c0 + 3) * LK];
      s += v0 * v0 + v1 * v1 + v2 * v2 + v3 * v3;
      uint2 w;
      w.x = f2bf(v0) | (f2bf(v1) << 16);
      w.y = f2bf(v2) | (f2bf(v3) << 16);
      *(uint2*)&Bt[col * LDT + c0] = w;  // byte addr 144*col + 2*c0, 8B aligned
    }
    atomicAdd(&norms[128 + col], s);
  }

  __syncthreads();  // tiles + norms complete (barrier drains lgkmcnt)

  // ---- MFMA: wave owns 64x64 (4x4 of 16x16x32), both frags are b128 reads ----
  const int wave = tid >> 6;
  const int lane = tid & 63;
  const int wm   = (wave >> 1) * 64;
  const int wn   = (wave & 1) * 64;
  const int n15  = lane & 15;
  const int qd   = lane >> 4;

  f32x4 acc[4][4];
#pragma unroll
  for (int mi = 0; mi < 4; ++mi)
#pragma unroll
    for (int ni = 0; ni < 4; ++ni)
      acc[mi][ni] = (f32x4){0.f, 0.f, 0.f, 0.f};

#pragma unroll
  for (int kk = 0; kk < DD; kk += 32) {
    short8 a[4], b[4];
#pragma unroll
    for (int mi = 0; mi < 4; ++mi)
      a[mi] = *(const short8*)&As[(wm + mi * 16 + n15) * LDT + kk + qd * 8];
#pragma unroll
    for (int ni = 0; ni < 4; ++ni)
      b[ni] = *(const short8*)&Bt[(wn + ni * 16 + n15) * LDT + kk + qd * 8];
#pragma unroll
    for (int mi = 0; mi < 4; ++mi)
#pragma unroll
      for (int ni = 0; ni < 4; ++ni)
        acc[mi][ni] = __builtin_amdgcn_mfma_f32_16x16x32_bf16(a[mi], b[ni], acc[mi][ni], 0, 0, 0);
  }

  // ---- epilogue: direct global stores from acc.
  // C/D map: col=lane&15, row=quad*4+reg. Per store-instr the wave writes
  // 4 rows x 64B contiguous; the ni loop completes each 128B line. ----
  f32x4 q2v[4];
  float k2s[4];
#pragma unroll
  for (int mi = 0; mi < 4; ++mi)
    q2v[mi] = *(const f32x4*)&norms[wm + mi * 16 + qd * 4];  // b128, bank-clean
#pragma unroll
  for (int ni = 0; ni < 4; ++ni)
    k2s[ni] = norms[128 + wn + ni * 16 + n15];  // broadcast across qd groups

  float* pob = out + ((size_t)bh * LQ + gm0 + wm + qd * 4) * (size_t)LK + gn0 + wn + n15;
#pragma unroll
  for (int mi = 0; mi < 4; ++mi) {
#pragma unroll
    for (int r = 0; r < 4; ++r) {
      float* pr = pob + (size_t)(mi * 16 + r) * LK;
      float q2 = q2v[mi][r];
#pragma unroll
      for (int ni = 0; ni < 4; ++ni)
        pr[ni * 16] = fmaf(-2.0f, acc[mi][ni][r], q2 + k2s[ni]);
    }
  }
}

extern "C" void kernel_launch(void* const* d_in, const int* in_sizes, int n_in,
                              void* d_out, int out_size, void* d_ws, size_t ws_size,
                              hipStream_t stream) {
  const float* Q = (const float*)d_in[0];
  const float* K = (const float*)d_in[1];
  float* out = (float*)d_out;
  dim3 grid(LK / TN, LQ / TM, BH);
  sg_kernel<<<grid, 256, 0, stream>>>(Q, K, out);
}